// Round 4
// baseline (3560.643 us; speedup 1.0000x reference)
//
#include <hip/hip_runtime.h>
#include <math.h>

#define HMM_B 32
#define HMM_T 8192
#define HMM_K 64

typedef float f2v __attribute__((ext_vector_type(2)));

#define LN2F 0.69314718055994531f
#define INV_LN2F 1.4426950408889634f
#define HALF_INV_LN2_SQRTF 0.8493218002880191f  /* sqrt(0.5/ln2) */
#define NEG_HALF_LOG_2PI 0.91893853320467274f

__device__ __forceinline__ float bcast0(float v) {
    return __int_as_float(__builtin_amdgcn_readfirstlane(__float_as_int(v)));
}
__device__ __forceinline__ float exp2_fast(float x) {
    float r; asm("v_exp_f32 %0, %1" : "=v"(r) : "v"(x)); return r;
}
__device__ __forceinline__ float log2_fast(float x) {
    float r; asm("v_log_f32 %0, %1" : "=v"(r) : "v"(x)); return r;
}

// paired matvec: uF_i = sum_j A[i][j]*wF[j], uB_i = sum_j A[i][j]*wB[j]
// single unrolled loop so the DS queue pipelines reads of BOTH chains.
__device__ __forceinline__ void matvec_pair(const f2v* __restrict__ areg,
                                            const float4* __restrict__ wvF,
                                            const float4* __restrict__ wvB,
                                            float& uF, float& uB) {
    f2v fa0 = {0.f,0.f}, fa1 = {0.f,0.f}, fa2 = {0.f,0.f}, fa3 = {0.f,0.f};
    f2v ba0 = {0.f,0.f}, ba1 = {0.f,0.f}, ba2 = {0.f,0.f}, ba3 = {0.f,0.f};
    #pragma unroll
    for (int j = 0; j < 8; ++j) {
        float4 fA = wvF[2 * j];
        float4 fB = wvF[2 * j + 1];
        float4 bA = wvB[2 * j];
        float4 bB = wvB[2 * j + 1];
        f2v t;
        t.x = fA.x; t.y = fA.y; fa0 += areg[4 * j + 0] * t;
        t.x = fA.z; t.y = fA.w; fa1 += areg[4 * j + 1] * t;
        t.x = bA.x; t.y = bA.y; ba0 += areg[4 * j + 0] * t;
        t.x = bA.z; t.y = bA.w; ba1 += areg[4 * j + 1] * t;
        t.x = fB.x; t.y = fB.y; fa2 += areg[4 * j + 2] * t;
        t.x = fB.z; t.y = fB.w; fa3 += areg[4 * j + 3] * t;
        t.x = bB.x; t.y = bB.y; ba2 += areg[4 * j + 2] * t;
        t.x = bB.z; t.y = bB.w; ba3 += areg[4 * j + 3] * t;
    }
    f2v sf = (fa0 + fa1) + (fa2 + fa3);
    f2v sb = (ba0 + ba1) + (ba2 + ba3);
    uF = sf.x + sf.y;
    uB = sb.x + sb.y;
}

// One wave per batch b: fwd chain and bwd chain interleaved in one instruction
// stream; each chain's LDS roundtrip latency hides under the other's issue work.
// A (areg) and obs_lds are shared. No in-loop barriers (single wave, DS in-order).
__global__ void __launch_bounds__(64, 1)
hmm_recur_pair(const float* __restrict__ obvs,
               const float* __restrict__ log_init,
               const float* __restrict__ transfer,
               const float* __restrict__ means,
               const float* __restrict__ log_stds,
               float* __restrict__ f_out,
               float* __restrict__ b_out)
{
    __shared__ float4 wbufF4[16];
    __shared__ float4 wbufB4[16];
    __shared__ float obs_lds[HMM_T + 4];   // pad: fwd prefetch reads index T (unused)
    const int lane = threadIdx.x;
    const int b    = blockIdx.x;

    const float mean_k   = means[lane];
    const float ls       = log_stds[lane];
    const float inv_std2 = __expf(-ls) * HALF_INV_LN2_SQRTF; // e2 = -((x-m)*is2)^2 + ce2 (log2 units)
    const float ce2      = (-ls - NEG_HALF_LOG_2PI) * INV_LN2F;
    const float li2      = log_init[lane] * INV_LN2F;

    f2v areg[32];
    const f2v* Arow = (const f2v*)(transfer + lane * HMM_K);
    #pragma unroll
    for (int j = 0; j < 32; ++j) areg[j] = Arow[j];

    const float* __restrict__ orow = obvs + (size_t)b * HMM_T;
    {
        const float4* o4 = (const float4*)orow;
        float4* l4 = (float4*)obs_lds;
        #pragma unroll 4
        for (int i = lane; i < HMM_T / 4; i += 64) l4[i] = o4[i];
    }
    __syncthreads();   // one-time (single wave -> waitcnt only)

    float* wbsF = ((float*)wbufF4) + lane;
    float* wbsB = ((float*)wbufB4) + lane;

    // ---- fwd prologue: f[0] = e2[0] + li2
    float x0 = obs_lds[0];
    float z0 = (x0 - mean_k) * inv_std2;
    float vF = fmaf(-z0, z0, ce2) + li2;
    float* poF = f_out + (size_t)b * HMM_T * HMM_K + lane;
    *poF = vF;
    float x1 = obs_lds[1];
    float z1 = (x1 - mean_k) * inv_std2;
    float e2cF = fmaf(-z1, z1, ce2);           // emission at t=1

    // ---- bwd prologue: b[T-1] = li2
    float vB = li2;
    float* poB = b_out + ((size_t)b * HMM_T + (HMM_T - 1)) * HMM_K + lane;
    *poB = vB;
    float xT = obs_lds[HMM_T - 1];
    float zT = (xT - mean_k) * inv_std2;
    float e2cB = fmaf(-zT, zT, ce2);           // emission at t=T-1

    for (int i = 0; i < HMM_T - 1; ++i) {
        // chain heads (independent): wF from vF, wB from vB+e2cB
        float dF = fminf(vF - bcast0(vF), 100.0f);
        float wF = exp2_fast(dF);
        float tmpB = vB + e2cB;                // b_{t+1} + e_{t+1}
        float dB = fminf(tmpB - bcast0(tmpB), 100.0f);
        float wB = exp2_fast(dB);
        *wbsF = wF;
        *wbsB = wB;
        __builtin_amdgcn_wave_barrier();
        float uF, uB;
        matvec_pair(areg, wbufF4, wbufB4, uF, uB);
        __builtin_amdgcn_wave_barrier();
        // tails + next-step emissions (issue while other chain's DS ops in flight)
        float xnF = obs_lds[i + 2];            // emission for fwd t+1  (pad covers i=T-2)
        float znF = (xnF - mean_k) * inv_std2;
        float e2nF = fmaf(-znF, znF, ce2);
        float xnB = obs_lds[HMM_T - 2 - i];    // emission for bwd next step
        float znB = (xnB - mean_k) * inv_std2;
        float e2nB = fmaf(-znB, znB, ce2);
        vF = e2cF + log2_fast(uF);             // f[i+1]
        poF += HMM_K;
        *poF = vF;
        vB = log2_fast(uB);                    // b[T-2-i]
        poB -= HMM_K;
        *poB = vB;
        e2cF = e2nF;
        e2cB = e2nB;
    }
}

// gamma = ln2 * (g2 - m - log2(sum exp2(g2 - m))), g2 = f2+b2 (log2 domain, offsets cancel)
__global__ void __launch_bounds__(256)
hmm_combine(const float* __restrict__ fbuf,
            const float* __restrict__ bbuf,
            float* __restrict__ out)
{
    const size_t row = (size_t)blockIdx.x * 4 + (threadIdx.x >> 6);
    const int lane = threadIdx.x & 63;
    const size_t idx = row * HMM_K + lane;
    float g = fbuf[idx] + bbuf[idx];
    float m = g;
    #pragma unroll
    for (int off = 32; off > 0; off >>= 1) m = fmaxf(m, __shfl_xor(m, off));
    float e = exp2_fast(g - m);
    float s = e;
    #pragma unroll
    for (int off = 32; off > 0; off >>= 1) s += __shfl_xor(s, off);
    out[idx] = LN2F * ((g - m) - log2_fast(s));
}

// ---------- fallback path (ws too small): fwd-only then bwd fused w/ combine ----------
__device__ __forceinline__ float matvec_row(const f2v* __restrict__ areg,
                                            const float4* __restrict__ wv) {
    f2v a0 = {0.f,0.f}, a1 = {0.f,0.f}, a2 = {0.f,0.f}, a3 = {0.f,0.f};
    #pragma unroll
    for (int j = 0; j < 8; ++j) {
        float4 wA = wv[2 * j];
        float4 wB = wv[2 * j + 1];
        f2v t;
        t.x = wA.x; t.y = wA.y; a0 += areg[4 * j + 0] * t;
        t.x = wA.z; t.y = wA.w; a1 += areg[4 * j + 1] * t;
        t.x = wB.x; t.y = wB.y; a2 += areg[4 * j + 2] * t;
        t.x = wB.z; t.y = wB.w; a3 += areg[4 * j + 3] * t;
    }
    f2v s = (a0 + a1) + (a2 + a3);
    return s.x + s.y;
}

__global__ void __launch_bounds__(64, 1)
hmm_fwd_single(const float* __restrict__ obvs,
               const float* __restrict__ log_init,
               const float* __restrict__ transfer,
               const float* __restrict__ means,
               const float* __restrict__ log_stds,
               float* __restrict__ f_out)
{
    __shared__ float4 wbuf4[16];
    __shared__ float obs_lds[HMM_T + 4];
    const int lane = threadIdx.x;
    const int b = blockIdx.x;
    const float mean_k   = means[lane];
    const float ls       = log_stds[lane];
    const float inv_std2 = __expf(-ls) * HALF_INV_LN2_SQRTF;
    const float ce2      = (-ls - NEG_HALF_LOG_2PI) * INV_LN2F;
    const float li2      = log_init[lane] * INV_LN2F;
    f2v areg[32];
    const f2v* Arow = (const f2v*)(transfer + lane * HMM_K);
    #pragma unroll
    for (int j = 0; j < 32; ++j) areg[j] = Arow[j];
    const float* __restrict__ orow = obvs + (size_t)b * HMM_T;
    {
        const float4* o4 = (const float4*)orow;
        float4* l4 = (float4*)obs_lds;
        #pragma unroll 4
        for (int i = lane; i < HMM_T / 4; i += 64) l4[i] = o4[i];
    }
    __syncthreads();
    float* wbs = ((float*)wbuf4) + lane;
    float x0 = obs_lds[0];
    float z0 = (x0 - mean_k) * inv_std2;
    float v  = fmaf(-z0, z0, ce2) + li2;
    float* po = f_out + (size_t)b * HMM_T * HMM_K + lane;
    *po = v;
    float x1 = obs_lds[1];
    float z1 = (x1 - mean_k) * inv_std2;
    float e2c = fmaf(-z1, z1, ce2);
    for (int t = 1; t < HMM_T; ++t) {
        float d = fminf(v - bcast0(v), 100.0f);
        float w = exp2_fast(d);
        *wbs = w;
        __builtin_amdgcn_wave_barrier();
        float xn = obs_lds[t + 1];
        float zn = (xn - mean_k) * inv_std2;
        float e2n = fmaf(-zn, zn, ce2);
        float u = matvec_row(areg, wbuf4);
        __builtin_amdgcn_wave_barrier();
        v = e2c + log2_fast(u);
        po += HMM_K;
        *po = v;
        e2c = e2n;
    }
}

__global__ void __launch_bounds__(64, 1)
hmm_bwd_combine(const float* __restrict__ obvs,
                const float* __restrict__ log_init,
                const float* __restrict__ transfer,
                const float* __restrict__ means,
                const float* __restrict__ log_stds,
                float* __restrict__ fout)
{
    __shared__ float4 wbuf4[16];
    __shared__ float obs_lds[HMM_T + 4];
    const int lane = threadIdx.x;
    const int b = blockIdx.x;
    const float mean_k   = means[lane];
    const float ls       = log_stds[lane];
    const float inv_std2 = __expf(-ls) * HALF_INV_LN2_SQRTF;
    const float ce2      = (-ls - NEG_HALF_LOG_2PI) * INV_LN2F;
    const float li2      = log_init[lane] * INV_LN2F;
    f2v areg[32];
    const f2v* Arow = (const f2v*)(transfer + lane * HMM_K);
    #pragma unroll
    for (int j = 0; j < 32; ++j) areg[j] = Arow[j];
    const float* __restrict__ orow = obvs + (size_t)b * HMM_T;
    {
        const float4* o4 = (const float4*)orow;
        float4* l4 = (float4*)obs_lds;
        #pragma unroll 4
        for (int i = lane; i < HMM_T / 4; i += 64) l4[i] = o4[i];
    }
    __syncthreads();
    float* wbs = ((float*)wbuf4) + lane;
    float bb = li2;
    for (int t = HMM_T - 1; t >= 0; --t) {
        const size_t base = ((size_t)b * HMM_T + t) * HMM_K;
        float g = fout[base + lane] + bb;
        float m = g;
        #pragma unroll
        for (int off = 32; off > 0; off >>= 1) m = fmaxf(m, __shfl_xor(m, off));
        float e = exp2_fast(g - m);
        float s = e;
        #pragma unroll
        for (int off = 32; off > 0; off >>= 1) s += __shfl_xor(s, off);
        fout[base + lane] = LN2F * ((g - m) - log2_fast(s));
        if (t > 0) {
            float xt = obs_lds[t];
            float zt = (xt - mean_k) * inv_std2;
            float tmp = bb + fmaf(-zt, zt, ce2);
            float d = fminf(tmp - bcast0(tmp), 100.0f);
            float wv = exp2_fast(d);
            *wbs = wv;
            __builtin_amdgcn_wave_barrier();
            float u = matvec_row(areg, wbuf4);
            __builtin_amdgcn_wave_barrier();
            bb = log2_fast(u);
        }
    }
}

extern "C" void kernel_launch(void* const* d_in, const int* in_sizes, int n_in,
                              void* d_out, int out_size, void* d_ws, size_t ws_size,
                              hipStream_t stream)
{
    const float* obvs     = (const float*)d_in[0];
    const float* log_init = (const float*)d_in[1];
    const float* transfer = (const float*)d_in[2];
    const float* means    = (const float*)d_in[3];
    const float* log_stds = (const float*)d_in[4];
    float* out = (float*)d_out;

    const size_t need = (size_t)HMM_B * HMM_T * HMM_K * sizeof(float);
    if (ws_size >= need) {
        float* bws = (float*)d_ws;
        hipLaunchKernelGGL(hmm_recur_pair, dim3(HMM_B), dim3(HMM_K), 0, stream,
                           obvs, log_init, transfer, means, log_stds, out, bws);
        hipLaunchKernelGGL(hmm_combine, dim3(HMM_B * HMM_T / 4), dim3(256), 0, stream,
                           out, bws, out);
    } else {
        hipLaunchKernelGGL(hmm_fwd_single, dim3(HMM_B), dim3(HMM_K), 0, stream,
                           obvs, log_init, transfer, means, log_stds, out);
        hipLaunchKernelGGL(hmm_bwd_combine, dim3(HMM_B), dim3(HMM_K), 0, stream,
                           obvs, log_init, transfer, means, log_stds, out);
    }
}

// Round 5
// 3160.181 us; speedup vs baseline: 1.1267x; 1.1267x over previous
//
#include <hip/hip_runtime.h>
#include <math.h>

#define HMM_B 32
#define HMM_T 8192
#define HMM_K 64

typedef float f2v __attribute__((ext_vector_type(2)));

#define LN2F 0.69314718055994531f
#define INV_LN2F 1.4426950408889634f
#define HALF_INV_LN2_SQRTF 0.8493218002880191f  /* sqrt(0.5/ln2) */
#define NEG_HALF_LOG_2PI 0.91893853320467274f

__device__ __forceinline__ float bcast0(float v) {
    return __int_as_float(__builtin_amdgcn_readfirstlane(__float_as_int(v)));
}
__device__ __forceinline__ float exp2_fast(float x) {
    float r; asm("v_exp_f32 %0, %1" : "=v"(r) : "v"(x)); return r;
}
__device__ __forceinline__ float log2_fast(float x) {
    float r; asm("v_log_f32 %0, %1" : "=v"(r) : "v"(x)); return r;
}

// ---- butterfly reduce-scatter over 64 lanes ----
// Precondition: lane j holds 64 floats in r[32] (f2v pairs) with XOR layout:
//   local f32 slot q  <->  global row g = q ^ j, value = A[g][j] * w_j.
// Postcondition: returns u_lane = sum_j A[lane][j] * w_j  (consumes r).
// Stages fold register-uniformly because the XOR layout makes the kept/sent
// halves the same register indices in every lane.
__device__ __forceinline__ float xfold(f2v* r, int bpidx) {
    // d=32: ds_bpermute with partner lane^32
    #pragma unroll
    for (int p = 0; p < 16; ++p) {
        f2v t;
        t.x = __int_as_float(__builtin_amdgcn_ds_bpermute(bpidx, __float_as_int(r[p + 16].x)));
        t.y = __int_as_float(__builtin_amdgcn_ds_bpermute(bpidx, __float_as_int(r[p + 16].y)));
        r[p] += t;
    }
    // d=16: ds_swizzle xor16 (BitMode: (16<<10)|0x1F)
    #pragma unroll
    for (int p = 0; p < 8; ++p) {
        f2v t;
        t.x = __int_as_float(__builtin_amdgcn_ds_swizzle(__float_as_int(r[p + 8].x), 0x401F));
        t.y = __int_as_float(__builtin_amdgcn_ds_swizzle(__float_as_int(r[p + 8].y), 0x401F));
        r[p] += t;
    }
    // d=8: xor8
    #pragma unroll
    for (int p = 0; p < 4; ++p) {
        f2v t;
        t.x = __int_as_float(__builtin_amdgcn_ds_swizzle(__float_as_int(r[p + 4].x), 0x201F));
        t.y = __int_as_float(__builtin_amdgcn_ds_swizzle(__float_as_int(r[p + 4].y), 0x201F));
        r[p] += t;
    }
    // d=4: xor4
    #pragma unroll
    for (int p = 0; p < 2; ++p) {
        f2v t;
        t.x = __int_as_float(__builtin_amdgcn_ds_swizzle(__float_as_int(r[p + 2].x), 0x101F));
        t.y = __int_as_float(__builtin_amdgcn_ds_swizzle(__float_as_int(r[p + 2].y), 0x101F));
        r[p] += t;
    }
    // d=2: DPP quad_perm [2,3,0,1] (xor2)
    {
        f2v t;
        t.x = __int_as_float(__builtin_amdgcn_update_dpp(0, __float_as_int(r[1].x), 0x4E, 0xF, 0xF, true));
        t.y = __int_as_float(__builtin_amdgcn_update_dpp(0, __float_as_int(r[1].y), 0x4E, 0xF, 0xF, true));
        r[0] += t;
    }
    // d=1: slot0 = global lane; partner's slot1 (= our global) via quad_perm [1,0,3,2] (xor1)
    float hi = __int_as_float(__builtin_amdgcn_update_dpp(0, __float_as_int(r[0].y), 0xB1, 0xF, 0xF, true));
    return r[0].x + hi;
}

// u_lane = sum_j A[lane][j] * w_j ; areg = XOR-layout column of A, w lane-local
__device__ __forceinline__ float matvec_x(const f2v* __restrict__ areg, float w, int bpidx) {
    f2v ww; ww.x = w; ww.y = w;
    f2v r[32];
    #pragma unroll
    for (int p = 0; p < 32; ++p) r[p] = areg[p] * ww;  // v_pk_mul_f32
    return xfold(r, bpidx);
}

// load A column `lane` in XOR layout: areg[p].{x,y} = A[(2p)^lane][lane], A[(2p+1)^lane][lane]
__device__ __forceinline__ void load_areg(const float* __restrict__ transfer, int lane, f2v* areg) {
    #pragma unroll
    for (int p = 0; p < 32; ++p) {
        areg[p].x = transfer[((2 * p) ^ lane) * HMM_K + lane];
        areg[p].y = transfer[((2 * p + 1) ^ lane) * HMM_K + lane];
    }
}

// blocks 0..B-1: forward (log2-f into f_out); blocks B..2B-1: backward (log2-b into b_out).
// One wave per block; chain is pure VALU/crosslane, no LDS roundtrip.
__global__ void __launch_bounds__(64, 1)
hmm_recur(const float* __restrict__ obvs,
          const float* __restrict__ log_init,
          const float* __restrict__ transfer,
          const float* __restrict__ means,
          const float* __restrict__ log_stds,
          float* __restrict__ f_out,
          float* __restrict__ b_out)
{
    __shared__ float obs_lds[HMM_T + 4];   // pad: fwd prefetch reads index T (unused)
    const int lane = threadIdx.x;
    const int blk  = blockIdx.x;
    const bool fwd = (blk < HMM_B);
    const int b    = fwd ? blk : blk - HMM_B;
    const int bpidx = (lane ^ 32) << 2;

    const float mean_k   = means[lane];
    const float ls       = log_stds[lane];
    const float inv_std2 = __expf(-ls) * HALF_INV_LN2_SQRTF; // e2 = -((x-m)*is2)^2 + ce2 (log2 units)
    const float ce2      = (-ls - NEG_HALF_LOG_2PI) * INV_LN2F;
    const float li2      = log_init[lane] * INV_LN2F;

    f2v areg[32];
    load_areg(transfer, lane, areg);

    const float* __restrict__ orow = obvs + (size_t)b * HMM_T;
    {
        const float4* o4 = (const float4*)orow;
        float4* l4 = (float4*)obs_lds;
        #pragma unroll 4
        for (int i = lane; i < HMM_T / 4; i += 64) l4[i] = o4[i];
    }
    __syncthreads();   // one-time (single wave -> waitcnt only)

    if (fwd) {
        float x0 = obs_lds[0];
        float z0 = (x0 - mean_k) * inv_std2;
        float v  = fmaf(-z0, z0, ce2) + li2;
        float* po = f_out + (size_t)b * HMM_T * HMM_K + lane;
        *po = v;
        float x1 = obs_lds[1];
        float z1 = (x1 - mean_k) * inv_std2;
        float e2c = fmaf(-z1, z1, ce2);
        for (int t = 1; t < HMM_T; ++t) {
            float d = fminf(v - bcast0(v), 100.0f);   // spread bounded (<~95 log2 units)
            float w = exp2_fast(d);
            float xn = obs_lds[t + 1];                // next emission, overlaps fold
            float zn = (xn - mean_k) * inv_std2;
            float e2n = fmaf(-zn, zn, ce2);
            float u = matvec_x(areg, w, bpidx);
            v = e2c + log2_fast(u);
            po += HMM_K;
            *po = v;                                  // fire-and-forget
            e2c = e2n;
        }
    } else {
        float v = li2;                                // b_{T-1} = log_initial_probs
        float* po = b_out + ((size_t)b * HMM_T + (HMM_T - 1)) * HMM_K + lane;
        *po = v;
        float xT = obs_lds[HMM_T - 1];
        float zT = (xT - mean_k) * inv_std2;
        float e2c = fmaf(-zT, zT, ce2);               // emission at t = T-1
        for (int t = HMM_T - 1; t >= 1; --t) {
            float tmp = v + e2c;                      // b_{t+1} + e_{t+1} (indices shifted)
            float d = fminf(tmp - bcast0(tmp), 100.0f);
            float w = exp2_fast(d);
            float xn = obs_lds[t - 1];
            float zn = (xn - mean_k) * inv_std2;
            float e2n = fmaf(-zn, zn, ce2);
            float u = matvec_x(areg, w, bpidx);
            v = log2_fast(u);                         // b[t-1]
            po -= HMM_K;
            *po = v;
            e2c = e2n;
        }
    }
}

// gamma = ln2 * (g2 - m - log2(sum exp2(g2 - m))), g2 = f2+b2 (log2 domain, offsets cancel)
__global__ void __launch_bounds__(256)
hmm_combine(const float* __restrict__ fbuf,
            const float* __restrict__ bbuf,
            float* __restrict__ out)
{
    const size_t row = (size_t)blockIdx.x * 4 + (threadIdx.x >> 6);
    const int lane = threadIdx.x & 63;
    const size_t idx = row * HMM_K + lane;
    float g = fbuf[idx] + bbuf[idx];
    float m = g;
    #pragma unroll
    for (int off = 32; off > 0; off >>= 1) m = fmaxf(m, __shfl_xor(m, off));
    float e = exp2_fast(g - m);
    float s = e;
    #pragma unroll
    for (int off = 32; off > 0; off >>= 1) s += __shfl_xor(s, off);
    out[idx] = LN2F * ((g - m) - log2_fast(s));
}

// ---------- fallback path (ws too small): fwd-only then bwd fused w/ combine ----------
__global__ void __launch_bounds__(64, 1)
hmm_fwd_single(const float* __restrict__ obvs,
               const float* __restrict__ log_init,
               const float* __restrict__ transfer,
               const float* __restrict__ means,
               const float* __restrict__ log_stds,
               float* __restrict__ f_out)
{
    __shared__ float obs_lds[HMM_T + 4];
    const int lane = threadIdx.x;
    const int b = blockIdx.x;
    const int bpidx = (lane ^ 32) << 2;
    const float mean_k   = means[lane];
    const float ls       = log_stds[lane];
    const float inv_std2 = __expf(-ls) * HALF_INV_LN2_SQRTF;
    const float ce2      = (-ls - NEG_HALF_LOG_2PI) * INV_LN2F;
    const float li2      = log_init[lane] * INV_LN2F;
    f2v areg[32];
    load_areg(transfer, lane, areg);
    const float* __restrict__ orow = obvs + (size_t)b * HMM_T;
    {
        const float4* o4 = (const float4*)orow;
        float4* l4 = (float4*)obs_lds;
        #pragma unroll 4
        for (int i = lane; i < HMM_T / 4; i += 64) l4[i] = o4[i];
    }
    __syncthreads();
    float x0 = obs_lds[0];
    float z0 = (x0 - mean_k) * inv_std2;
    float v  = fmaf(-z0, z0, ce2) + li2;
    float* po = f_out + (size_t)b * HMM_T * HMM_K + lane;
    *po = v;
    float x1 = obs_lds[1];
    float z1 = (x1 - mean_k) * inv_std2;
    float e2c = fmaf(-z1, z1, ce2);
    for (int t = 1; t < HMM_T; ++t) {
        float d = fminf(v - bcast0(v), 100.0f);
        float w = exp2_fast(d);
        float xn = obs_lds[t + 1];
        float zn = (xn - mean_k) * inv_std2;
        float e2n = fmaf(-zn, zn, ce2);
        float u = matvec_x(areg, w, bpidx);
        v = e2c + log2_fast(u);
        po += HMM_K;
        *po = v;
        e2c = e2n;
    }
}

__global__ void __launch_bounds__(64, 1)
hmm_bwd_combine(const float* __restrict__ obvs,
                const float* __restrict__ log_init,
                const float* __restrict__ transfer,
                const float* __restrict__ means,
                const float* __restrict__ log_stds,
                float* __restrict__ fout)
{
    __shared__ float obs_lds[HMM_T + 4];
    const int lane = threadIdx.x;
    const int b = blockIdx.x;
    const int bpidx = (lane ^ 32) << 2;
    const float mean_k   = means[lane];
    const float ls       = log_stds[lane];
    const float inv_std2 = __expf(-ls) * HALF_INV_LN2_SQRTF;
    const float ce2      = (-ls - NEG_HALF_LOG_2PI) * INV_LN2F;
    const float li2      = log_init[lane] * INV_LN2F;
    f2v areg[32];
    load_areg(transfer, lane, areg);
    const float* __restrict__ orow = obvs + (size_t)b * HMM_T;
    {
        const float4* o4 = (const float4*)orow;
        float4* l4 = (float4*)obs_lds;
        #pragma unroll 4
        for (int i = lane; i < HMM_T / 4; i += 64) l4[i] = o4[i];
    }
    __syncthreads();
    float bb = li2;
    for (int t = HMM_T - 1; t >= 0; --t) {
        const size_t base = ((size_t)b * HMM_T + t) * HMM_K;
        float g = fout[base + lane] + bb;
        float m = g;
        #pragma unroll
        for (int off = 32; off > 0; off >>= 1) m = fmaxf(m, __shfl_xor(m, off));
        float e = exp2_fast(g - m);
        float s = e;
        #pragma unroll
        for (int off = 32; off > 0; off >>= 1) s += __shfl_xor(s, off);
        fout[base + lane] = LN2F * ((g - m) - log2_fast(s));
        if (t > 0) {
            float xt = obs_lds[t];
            float zt = (xt - mean_k) * inv_std2;
            float tmp = bb + fmaf(-zt, zt, ce2);
            float d = fminf(tmp - bcast0(tmp), 100.0f);
            float w = exp2_fast(d);
            bb = log2_fast(matvec_x(areg, w, bpidx));
        }
    }
}

extern "C" void kernel_launch(void* const* d_in, const int* in_sizes, int n_in,
                              void* d_out, int out_size, void* d_ws, size_t ws_size,
                              hipStream_t stream)
{
    const float* obvs     = (const float*)d_in[0];
    const float* log_init = (const float*)d_in[1];
    const float* transfer = (const float*)d_in[2];
    const float* means    = (const float*)d_in[3];
    const float* log_stds = (const float*)d_in[4];
    float* out = (float*)d_out;

    const size_t need = (size_t)HMM_B * HMM_T * HMM_K * sizeof(float);
    if (ws_size >= need) {
        float* bws = (float*)d_ws;
        hipLaunchKernelGGL(hmm_recur, dim3(2 * HMM_B), dim3(HMM_K), 0, stream,
                           obvs, log_init, transfer, means, log_stds, out, bws);
        hipLaunchKernelGGL(hmm_combine, dim3(HMM_B * HMM_T / 4), dim3(256), 0, stream,
                           out, bws, out);
    } else {
        hipLaunchKernelGGL(hmm_fwd_single, dim3(HMM_B), dim3(HMM_K), 0, stream,
                           obvs, log_init, transfer, means, log_stds, out);
        hipLaunchKernelGGL(hmm_bwd_combine, dim3(HMM_B), dim3(HMM_K), 0, stream,
                           obvs, log_init, transfer, means, log_stds, out);
    }
}

// Round 6
// 315.599 us; speedup vs baseline: 11.2822x; 10.0133x over previous
//
#include <hip/hip_runtime.h>
#include <math.h>

#define HMM_B 32
#define HMM_T 8192
#define HMM_K 64
#define L_EFF 512
#define L_WARM 384
#define C_CHUNKS (HMM_T / L_EFF)   /* 16 */

typedef float f2v __attribute__((ext_vector_type(2)));

#define LN2F 0.69314718055994531f
#define INV_LN2F 1.4426950408889634f
#define HALF_INV_LN2_SQRTF 0.8493218002880191f  /* sqrt(0.5/ln2) */
#define NEG_HALF_LOG_2PI 0.91893853320467274f

__device__ __forceinline__ float bcast0(float v) {
    return __int_as_float(__builtin_amdgcn_readfirstlane(__float_as_int(v)));
}
__device__ __forceinline__ float exp2_fast(float x) {
    float r; asm("v_exp_f32 %0, %1" : "=v"(r) : "v"(x)); return r;
}
__device__ __forceinline__ float log2_fast(float x) {
    float r; asm("v_log_f32 %0, %1" : "=v"(r) : "v"(x)); return r;
}

// u_i = sum_j A[i][j]*w[j]; A register-resident as float2 pairs -> v_pk_fma_f32
__device__ __forceinline__ float matvec_row(const f2v* __restrict__ areg,
                                            const float4* __restrict__ wv) {
    f2v a0 = {0.f,0.f}, a1 = {0.f,0.f}, a2 = {0.f,0.f}, a3 = {0.f,0.f};
    #pragma unroll
    for (int j = 0; j < 8; ++j) {
        float4 wA = wv[2 * j];
        float4 wB = wv[2 * j + 1];
        f2v t;
        t.x = wA.x; t.y = wA.y; a0 += areg[4 * j + 0] * t;
        t.x = wA.z; t.y = wA.w; a1 += areg[4 * j + 1] * t;
        t.x = wB.x; t.y = wB.y; a2 += areg[4 * j + 2] * t;
        t.x = wB.z; t.y = wB.w; a3 += areg[4 * j + 3] * t;
    }
    f2v s = (a0 + a1) + (a2 + a3);
    return s.x + s.y;
}

// one fwd step: v=f_t -> f_{t+1}; e2c holds emission(t+1); prefetches emission(t+2)
#define FWD_STEP { \
    float d_ = fminf(v - bcast0(v), 100.0f); \
    float w_ = exp2_fast(d_); \
    *wbs = w_; \
    __builtin_amdgcn_wave_barrier(); \
    float xn_ = ow[t + 1]; \
    float zn_ = (xn_ - mean_k) * inv_std2; \
    float e2n_ = fmaf(-zn_, zn_, ce2); \
    float u_ = matvec_row(areg, wbuf4); \
    __builtin_amdgcn_wave_barrier(); \
    v = e2c + log2_fast(u_); \
    e2c = e2n_; }

// one bwd step: v=b_t -> b_{t-1}; e2c holds emission(t); prefetches emission(t-1)
#define BWD_STEP { \
    float tmp_ = v + e2c; \
    float d_ = fminf(tmp_ - bcast0(tmp_), 100.0f); \
    float w_ = exp2_fast(d_); \
    *wbs = w_; \
    __builtin_amdgcn_wave_barrier(); \
    float xn_ = ow[t - 1]; \
    float zn_ = (xn_ - mean_k) * inv_std2; \
    float e2n_ = fmaf(-zn_, zn_, ce2); \
    float u_ = matvec_row(areg, wbuf4); \
    __builtin_amdgcn_wave_barrier(); \
    v = log2_fast(u_); \
    e2c = e2n_; }

// Chunked recurrences with warmup. Blocks [0, B*C): fwd chunk (b = blk>>4, c = blk&15).
// Blocks [B*C, 2*B*C): bwd chunk. Warm chunks start from a uniform vector L_WARM
// steps outside their window; the Hilbert contraction of A makes the direction
// converge; the scale offset cancels in the final per-row logsumexp.
__global__ void __launch_bounds__(64, 1)
hmm_recur_chunk(const float* __restrict__ obvs,
                const float* __restrict__ log_init,
                const float* __restrict__ transfer,
                const float* __restrict__ means,
                const float* __restrict__ log_stds,
                float* __restrict__ f_out,
                float* __restrict__ b_out)
{
    __shared__ float4 wbuf4[16];
    __shared__ float obs_lds[1024];
    const int lane = threadIdx.x;
    int blk = blockIdx.x;
    const bool is_fwd = blk < HMM_B * C_CHUNKS;
    if (!is_fwd) blk -= HMM_B * C_CHUNKS;
    const int b  = blk >> 4;
    const int c  = blk & (C_CHUNKS - 1);
    const int t0 = c * L_EFF;
    const int tE = t0 + L_EFF;

    const float mean_k   = means[lane];
    const float ls       = log_stds[lane];
    const float inv_std2 = __expf(-ls) * HALF_INV_LN2_SQRTF; // e2 = -((x-m)*is2)^2 + ce2 (log2 units)
    const float ce2      = (-ls - NEG_HALF_LOG_2PI) * INV_LN2F;
    const float li2      = log_init[lane] * INV_LN2F;

    f2v areg[32];
    const f2v* Arow = (const f2v*)(transfer + lane * HMM_K);
    #pragma unroll
    for (int j = 0; j < 32; ++j) areg[j] = Arow[j];

    const float* __restrict__ orow = obvs + (size_t)b * HMM_T;
    const int w_lo = is_fwd ? ((c == 0) ? 0 : ((t0 - L_WARM) & ~3)) : t0;
    int nfl = HMM_T - w_lo; if (nfl > 1024) nfl = 1024;
    {
        const float4* o4 = (const float4*)(orow + w_lo);
        float4* l4 = (float4*)obs_lds;
        for (int i = lane; i < (nfl >> 2); i += 64) l4[i] = o4[i];
    }
    __syncthreads();                       // single wave -> waitcnt only
    const float* ow = obs_lds - w_lo;      // ow[t] valid for t in [w_lo, w_lo+nfl)
    float* wbs = ((float*)wbuf4) + lane;

    if (is_fwd) {
        const int t_s = (c == 0) ? 0 : (t0 - L_WARM);
        float x0 = ow[t_s];
        float z0 = (x0 - mean_k) * inv_std2;
        float v  = fmaf(-z0, z0, ce2) + ((c == 0) ? li2 : 0.0f);  // uniform prior for warm chunks
        float* po;
        if (c == 0) {
            po = f_out + ((size_t)b * HMM_T + 0) * HMM_K + lane;
            *po = v;                       // row 0 stored
        } else {
            po = f_out + ((size_t)b * HMM_T + (t0 - 1)) * HMM_K + lane;  // not written
        }
        float x1 = ow[t_s + 1];
        float z1 = (x1 - mean_k) * inv_std2;
        float e2c = fmaf(-z1, z1, ce2);
        int t = t_s + 1;
        for (; t < t0; ++t) {              // warmup (empty for c==0)
            FWD_STEP
        }
        for (; t < tE; ++t) {              // stored region
            FWD_STEP
            po += HMM_K; *po = v;
        }
    } else {
        const bool last = (c == C_CHUNKS - 1);
        int t = last ? (HMM_T - 1) : (tE - 1 + L_WARM);
        float v;
        float* po;
        if (last) {
            v = li2;                       // b_{T-1} = log_initial_probs (exact)
            po = b_out + ((size_t)b * HMM_T + (HMM_T - 1)) * HMM_K + lane;
            *po = v;
        } else {
            v = 0.0f;                      // uniform init at t_w
            po = b_out + ((size_t)b * HMM_T + tE) * HMM_K + lane;  // one row above first store
        }
        float xs = ow[t];
        float zs = (xs - mean_k) * inv_std2;
        float e2c = fmaf(-zs, zs, ce2);
        for (; t > tE; --t) {              // warmup (empty for last chunk)
            BWD_STEP
        }
        for (; t > t0; --t) {              // stored region: writes rows tE-1 .. t0
            BWD_STEP
            po -= HMM_K; *po = v;
        }
    }
}

// gamma = ln2 * (g2 - m - log2(sum exp2(g2 - m))), g2 = f2+b2 (log2 domain, offsets cancel)
__global__ void __launch_bounds__(256)
hmm_combine(const float* __restrict__ fbuf,
            const float* __restrict__ bbuf,
            float* __restrict__ out)
{
    const size_t row = (size_t)blockIdx.x * 4 + (threadIdx.x >> 6);
    const int lane = threadIdx.x & 63;
    const size_t idx = row * HMM_K + lane;
    float g = fbuf[idx] + bbuf[idx];
    float m = g;
    #pragma unroll
    for (int off = 32; off > 0; off >>= 1) m = fmaxf(m, __shfl_xor(m, off));
    float e = exp2_fast(g - m);
    float s = e;
    #pragma unroll
    for (int off = 32; off > 0; off >>= 1) s += __shfl_xor(s, off);
    out[idx] = LN2F * ((g - m) - log2_fast(s));
}

// ---------- fallback path (ws too small): full-T serial fwd, then bwd fused w/ combine ----------
__global__ void __launch_bounds__(64, 1)
hmm_fwd_single(const float* __restrict__ obvs,
               const float* __restrict__ log_init,
               const float* __restrict__ transfer,
               const float* __restrict__ means,
               const float* __restrict__ log_stds,
               float* __restrict__ f_out)
{
    __shared__ float4 wbuf4[16];
    __shared__ float obs_lds_full[HMM_T + 4];
    const int lane = threadIdx.x;
    const int b = blockIdx.x;
    const float mean_k   = means[lane];
    const float ls       = log_stds[lane];
    const float inv_std2 = __expf(-ls) * HALF_INV_LN2_SQRTF;
    const float ce2      = (-ls - NEG_HALF_LOG_2PI) * INV_LN2F;
    const float li2      = log_init[lane] * INV_LN2F;
    f2v areg[32];
    const f2v* Arow = (const f2v*)(transfer + lane * HMM_K);
    #pragma unroll
    for (int j = 0; j < 32; ++j) areg[j] = Arow[j];
    const float* __restrict__ orow = obvs + (size_t)b * HMM_T;
    {
        const float4* o4 = (const float4*)orow;
        float4* l4 = (float4*)obs_lds_full;
        #pragma unroll 4
        for (int i = lane; i < HMM_T / 4; i += 64) l4[i] = o4[i];
    }
    __syncthreads();
    const float* ow = obs_lds_full;
    float* wbs = ((float*)wbuf4) + lane;
    float x0 = ow[0];
    float z0 = (x0 - mean_k) * inv_std2;
    float v  = fmaf(-z0, z0, ce2) + li2;
    float* po = f_out + (size_t)b * HMM_T * HMM_K + lane;
    *po = v;
    float x1 = ow[1];
    float z1 = (x1 - mean_k) * inv_std2;
    float e2c = fmaf(-z1, z1, ce2);
    for (int t = 1; t < HMM_T; ++t) {
        FWD_STEP
        po += HMM_K; *po = v;
    }
}

__global__ void __launch_bounds__(64, 1)
hmm_bwd_combine(const float* __restrict__ obvs,
                const float* __restrict__ log_init,
                const float* __restrict__ transfer,
                const float* __restrict__ means,
                const float* __restrict__ log_stds,
                float* __restrict__ fout)
{
    __shared__ float4 wbuf4[16];
    __shared__ float obs_lds_full[HMM_T + 4];
    const int lane = threadIdx.x;
    const int b = blockIdx.x;
    const float mean_k   = means[lane];
    const float ls       = log_stds[lane];
    const float inv_std2 = __expf(-ls) * HALF_INV_LN2_SQRTF;
    const float ce2      = (-ls - NEG_HALF_LOG_2PI) * INV_LN2F;
    const float li2      = log_init[lane] * INV_LN2F;
    f2v areg[32];
    const f2v* Arow = (const f2v*)(transfer + lane * HMM_K);
    #pragma unroll
    for (int j = 0; j < 32; ++j) areg[j] = Arow[j];
    const float* __restrict__ orow = obvs + (size_t)b * HMM_T;
    {
        const float4* o4 = (const float4*)orow;
        float4* l4 = (float4*)obs_lds_full;
        #pragma unroll 4
        for (int i = lane; i < HMM_T / 4; i += 64) l4[i] = o4[i];
    }
    __syncthreads();
    const float* ow = obs_lds_full;
    float* wbs = ((float*)wbuf4) + lane;
    float bb = li2;
    for (int t = HMM_T - 1; t >= 0; --t) {
        const size_t base = ((size_t)b * HMM_T + t) * HMM_K;
        float g = fout[base + lane] + bb;
        float m = g;
        #pragma unroll
        for (int off = 32; off > 0; off >>= 1) m = fmaxf(m, __shfl_xor(m, off));
        float e = exp2_fast(g - m);
        float s = e;
        #pragma unroll
        for (int off = 32; off > 0; off >>= 1) s += __shfl_xor(s, off);
        fout[base + lane] = LN2F * ((g - m) - log2_fast(s));
        if (t > 0) {
            float xt = ow[t];
            float zt = (xt - mean_k) * inv_std2;
            float tmp = bb + fmaf(-zt, zt, ce2);
            float d = fminf(tmp - bcast0(tmp), 100.0f);
            float w = exp2_fast(d);
            *wbs = w;
            __builtin_amdgcn_wave_barrier();
            float u = matvec_row(areg, wbuf4);
            __builtin_amdgcn_wave_barrier();
            bb = log2_fast(u);
        }
    }
}

extern "C" void kernel_launch(void* const* d_in, const int* in_sizes, int n_in,
                              void* d_out, int out_size, void* d_ws, size_t ws_size,
                              hipStream_t stream)
{
    const float* obvs     = (const float*)d_in[0];
    const float* log_init = (const float*)d_in[1];
    const float* transfer = (const float*)d_in[2];
    const float* means    = (const float*)d_in[3];
    const float* log_stds = (const float*)d_in[4];
    float* out = (float*)d_out;

    const size_t need = (size_t)HMM_B * HMM_T * HMM_K * sizeof(float);
    if (ws_size >= need) {
        float* bws = (float*)d_ws;
        hipLaunchKernelGGL(hmm_recur_chunk, dim3(2 * HMM_B * C_CHUNKS), dim3(HMM_K), 0, stream,
                           obvs, log_init, transfer, means, log_stds, out, bws);
        hipLaunchKernelGGL(hmm_combine, dim3(HMM_B * HMM_T / 4), dim3(256), 0, stream,
                           out, bws, out);
    } else {
        hipLaunchKernelGGL(hmm_fwd_single, dim3(HMM_B), dim3(HMM_K), 0, stream,
                           obvs, log_init, transfer, means, log_stds, out);
        hipLaunchKernelGGL(hmm_bwd_combine, dim3(HMM_B), dim3(HMM_K), 0, stream,
                           obvs, log_init, transfer, means, log_stds, out);
    }
}